// Round 1
// baseline (163.538 us; speedup 1.0000x reference)
//
#include <hip/hip_runtime.h>

// IF spiking neuron, T=3 timesteps fused.
// x: [3, 4, 2048, 4096] f32; out: [3, 4, 2048, 4096] f32.
// Elementwise over the plane (33,554,432 elems): m = 0.5*thr + x0+x1+x2;
// 3x {spike = m>thr; m -= spike*thr; out_t = thr*spike}.

__global__ __launch_bounds__(256) void IF_80702435492066_kernel(
    const float4* __restrict__ x,
    const float* __restrict__ alpha_p,
    float4* __restrict__ out,
    long long n4)  // float4 elements per timestep plane
{
    const float thr = alpha_p[0];
    const float half_thr = 0.5f * thr;

    long long i = (long long)blockIdx.x * blockDim.x + threadIdx.x;
    const long long stride = (long long)gridDim.x * blockDim.x;

    for (; i < n4; i += stride) {
        const float4 a = x[i];
        const float4 b = x[i + n4];
        const float4 c = x[i + 2 * n4];

        float4 o0, o1, o2;

        #define STEP3(COMP)                                              \
            {                                                            \
                float m = half_thr + ((a.COMP + b.COMP) + c.COMP);       \
                float s0 = (m > thr) ? thr : 0.0f; m -= s0;              \
                float s1 = (m > thr) ? thr : 0.0f; m -= s1;              \
                float s2 = (m > thr) ? thr : 0.0f;                       \
                o0.COMP = s0; o1.COMP = s1; o2.COMP = s2;                \
            }

        STEP3(x)
        STEP3(y)
        STEP3(z)
        STEP3(w)
        #undef STEP3

        out[i]          = o0;
        out[i + n4]     = o1;
        out[i + 2 * n4] = o2;
    }
}

extern "C" void kernel_launch(void* const* d_in, const int* in_sizes, int n_in,
                              void* d_out, int out_size, void* d_ws, size_t ws_size,
                              hipStream_t stream) {
    const float* x     = (const float*)d_in[0];
    const float* alpha = (const float*)d_in[1];
    float* out         = (float*)d_out;

    // in_sizes[0] = 3 * plane; plane = 4*2048*4096 = 33,554,432 (divisible by 4)
    const long long plane = (long long)in_sizes[0] / 3;
    const long long n4 = plane / 4;

    const int block = 256;
    const int grid = 2048;  // grid-stride: 16 float4 iters/thread

    IF_80702435492066_kernel<<<grid, block, 0, stream>>>(
        (const float4*)x, alpha, (float4*)out, n4);
}

// Round 3
// 148.128 us; speedup vs baseline: 1.1040x; 1.1040x over previous
//
#include <hip/hip_runtime.h>

// IF spiking neuron, T=3 timesteps fused.
// x: [3, 4, 2048, 4096] f32; out: [3, 4, 2048, 4096] f32.
// Streaming elementwise: m = 0.5*thr + x0+x1+x2; 3x {s=m>thr?thr:0; m-=s}.
// Non-temporal loads/stores (no reuse -> don't allocate in cache),
// 2x float4 unroll per thread for memory-level parallelism.
// NOTE: use clang native ext_vector_type, not HIP_vector_type — the
// nontemporal builtins reject struct-wrapped vectors.

typedef float f32x4 __attribute__((ext_vector_type(4)));

__global__ __launch_bounds__(256) void IF_80702435492066_kernel(
    const f32x4* __restrict__ x,
    const float* __restrict__ alpha_p,
    f32x4* __restrict__ out,
    long long n4)  // f32x4 elements per timestep plane
{
    const float thr = alpha_p[0];
    const float half_thr = 0.5f * thr;

    const long long stride = (long long)gridDim.x * blockDim.x;
    long long i = (long long)blockIdx.x * blockDim.x + threadIdx.x;

    #define PROCESS(J)                                                      \
        {                                                                   \
            const long long j = (J);                                        \
            const f32x4 a = __builtin_nontemporal_load(&x[j]);              \
            const f32x4 b = __builtin_nontemporal_load(&x[j + n4]);         \
            const f32x4 c = __builtin_nontemporal_load(&x[j + 2 * n4]);     \
            f32x4 o0, o1, o2;                                               \
            _Pragma("unroll")                                               \
            for (int k = 0; k < 4; ++k) {                                   \
                float m = half_thr + ((a[k] + b[k]) + c[k]);                \
                float s0 = (m > thr) ? thr : 0.0f; m -= s0;                 \
                float s1 = (m > thr) ? thr : 0.0f; m -= s1;                 \
                float s2 = (m > thr) ? thr : 0.0f;                          \
                o0[k] = s0; o1[k] = s1; o2[k] = s2;                         \
            }                                                               \
            __builtin_nontemporal_store(o0, &out[j]);                       \
            __builtin_nontemporal_store(o1, &out[j + n4]);                  \
            __builtin_nontemporal_store(o2, &out[j + 2 * n4]);              \
        }

    for (long long j0 = i; j0 < n4; j0 += 2 * stride) {
        PROCESS(j0)
        const long long j1 = j0 + stride;
        if (j1 < n4) PROCESS(j1)
    }
    #undef PROCESS
}

extern "C" void kernel_launch(void* const* d_in, const int* in_sizes, int n_in,
                              void* d_out, int out_size, void* d_ws, size_t ws_size,
                              hipStream_t stream) {
    const float* x     = (const float*)d_in[0];
    const float* alpha = (const float*)d_in[1];
    float* out         = (float*)d_out;

    // in_sizes[0] = 3 * plane; plane = 4*2048*4096 = 33,554,432 (divisible by 4)
    const long long plane = (long long)in_sizes[0] / 3;
    const long long n4 = plane / 4;

    const int block = 256;
    const int grid = 2048;  // 8 blocks/CU resident; 8 unroll-2 iters/thread

    IF_80702435492066_kernel<<<grid, block, 0, stream>>>(
        (const f32x4*)x, alpha, (f32x4*)out, n4);
}